// Round 1
// baseline (1071.385 us; speedup 1.0000x reference)
//
#include <hip/hip_runtime.h>

#define B_ 8
#define T_ 4096
#define H_ 1024
#define NH_ 16
#define HD_ 64
#define M_ (B_*T_)   // 32768

typedef __attribute__((ext_vector_type(8))) short short8;
typedef __attribute__((ext_vector_type(4))) float floatx4;

__device__ __forceinline__ float bf2f(short s) {
  union { unsigned u; float f; } v; v.u = ((unsigned)(unsigned short)s) << 16; return v.f;
}
__device__ __forceinline__ short f2bf(float f) {
  union { float f; unsigned u; } v; v.f = f;
  unsigned r = (v.u + 0x7fffu + ((v.u >> 16) & 1u)) >> 16;
  return (short)r;
}

// ---------------- cast f32 -> bf16, 8 elems/thread ----------------
__global__ __launch_bounds__(256) void cast_f32_to_bf16(
    const float* __restrict__ src, short* __restrict__ dst, long n8) {
  long i = (long)blockIdx.x * 256 + threadIdx.x;
  if (i >= n8) return;
  const float4* s4 = (const float4*)src + i * 2;
  float4 a = s4[0], b = s4[1];
  short8 o;
  o[0] = f2bf(a.x); o[1] = f2bf(a.y); o[2] = f2bf(a.z); o[3] = f2bf(a.w);
  o[4] = f2bf(b.x); o[5] = f2bf(b.y); o[6] = f2bf(b.z); o[7] = f2bf(b.w);
  *((short8*)dst + i) = o;
}

// ---------------- 128x128 bf16 GEMM, C = A @ Bw^T (+bias, +resid) -------------
// A: [Mb, K] bf16 row-major, Bw: [N, K] bf16 row-major (B-transposed layout).
// EPI==0: out bf16 = acc + bias ; EPI==1: out f32 = acc + bias + resid(bf16)
template<int EPI>
__global__ __launch_bounds__(256, 2) void gemm_bt(
    const short* __restrict__ A, const short* __restrict__ Bw,
    const float* __restrict__ bias, const short* __restrict__ resid,
    void* __restrict__ out, int K, int N,
    long sA, long sB, long sO)
{
  __shared__ alignas(16) short As[128 * 64];
  __shared__ alignas(16) short Bs[128 * 64];
  const int tid = threadIdx.x;
  const int lane = tid & 63, wid = tid >> 6;
  const int bz = blockIdx.z;
  const short* Ab = A + (long)bz * sA;
  const short* Bb = Bw + (long)bz * sB;
  const int row0 = blockIdx.x * 128, col0 = blockIdx.y * 128;
  floatx4 acc[4][4] = {};
  const int wr = wid >> 1, wc = wid & 1;

  for (int k0 = 0; k0 < K; k0 += 64) {
    // stage A,B tiles (128x64 bf16 each) via direct global->LDS, 16B/lane
#pragma unroll
    for (int it = 0; it < 4; ++it) {
      int c = it * 4 + wid;          // chunk 0..15, wave-uniform
      int e = c * 512 + lane * 8;    // element index within tile
      int r = e >> 6, cc = e & 63;
      __builtin_amdgcn_global_load_lds(
          (const __attribute__((address_space(1))) void*)(Ab + (long)(row0 + r) * K + k0 + cc),
          (__attribute__((address_space(3))) void*)(As + c * 512), 16, 0, 0);
      __builtin_amdgcn_global_load_lds(
          (const __attribute__((address_space(1))) void*)(Bb + (long)(col0 + r) * K + k0 + cc),
          (__attribute__((address_space(3))) void*)(Bs + c * 512), 16, 0, 0);
    }
    __syncthreads();
#pragma unroll
    for (int kk = 0; kk < 2; ++kk) {
      const int kof = kk * 32 + (lane >> 4) * 8;
      short8 af[4], bfv[4];
#pragma unroll
      for (int m = 0; m < 4; ++m)
        af[m] = *(const short8*)(As + (wr * 64 + m * 16 + (lane & 15)) * 64 + kof);
#pragma unroll
      for (int n = 0; n < 4; ++n)
        bfv[n] = *(const short8*)(Bs + (wc * 64 + n * 16 + (lane & 15)) * 64 + kof);
#pragma unroll
      for (int m = 0; m < 4; ++m)
#pragma unroll
        for (int n = 0; n < 4; ++n)
          acc[m][n] = __builtin_amdgcn_mfma_f32_16x16x32_bf16(af[m], bfv[n], acc[m][n], 0, 0, 0);
    }
    __syncthreads();
  }
  // epilogue: C layout col=lane&15, row=(lane>>4)*4+i
#pragma unroll
  for (int n = 0; n < 4; ++n) {
    const int gc = col0 + wc * 64 + n * 16 + (lane & 15);
    const float bv = bias[gc];
#pragma unroll
    for (int m = 0; m < 4; ++m) {
      const int rbase = row0 + wr * 64 + m * 16 + ((lane >> 4) << 2);
#pragma unroll
      for (int i = 0; i < 4; ++i) {
        long idx = (long)bz * sO + (long)(rbase + i) * N + gc;
        float v = acc[m][n][i] + bv;
        if (EPI == 0) ((short*)out)[idx] = f2bf(v);
        else          ((float*)out)[idx] = v + bf2f(resid[idx]);
      }
    }
  }
}

// ---------------- score GEMM: S[b,n,t] = (X[b,t,:] . W2[(b),n,:] + bias[n])*0.125 ----
// grid (T/64, B), 256 thr; wave handles 16 rows; N=16 fits one 16x16x32 MFMA tile.
__global__ __launch_bounds__(256) void score_gemm(
    const short* __restrict__ X, const short* __restrict__ W2,
    const float* __restrict__ bias2, float* __restrict__ S, long sW)
{
  const int b = blockIdx.y;
  const int lane = threadIdx.x & 63, wid = threadIdx.x >> 6;
  const int t0 = blockIdx.x * 64 + wid * 16;
  const short* Xb = X + ((long)b * T_ + t0) * H_;
  const short* Wb = W2 + (long)b * sW;
  floatx4 acc = {};
  const int rr = lane & 15;
  const int kof = (lane >> 4) * 8;
#pragma unroll 8
  for (int k0 = 0; k0 < H_; k0 += 32) {
    short8 a = *(const short8*)(Xb + (long)rr * H_ + k0 + kof);
    short8 w = *(const short8*)(Wb + (long)rr * H_ + k0 + kof);
    acc = __builtin_amdgcn_mfma_f32_16x16x32_bf16(a, w, acc, 0, 0, 0);
  }
  const int n = lane & 15;
  const float bv = bias2[n];
#pragma unroll
  for (int i = 0; i < 4; ++i) {
    int t = t0 + (lane >> 4) * 4 + i;
    S[((long)b * NH_ + n) * T_ + t] = (acc[i] + bv) * 0.125f;
  }
}

// ---------------- softmax over T + pooled vector ----------------
// grid = B*NH blocks of 256. P[b, n*64+d] = (sum_t softmax(S)[t] * X[b,t,n*64+d]) * pscale?
__global__ __launch_bounds__(256) void softmax_pool(
    const float* __restrict__ S, const float* __restrict__ mask,
    const short* __restrict__ X, const float* __restrict__ pscale,
    float* __restrict__ P)
{
  const int bn = blockIdx.x, b = bn >> 4, n = bn & 15;
  const float* Srow = S + (long)bn * T_;
  const float* mrow = mask + (long)b * T_;
  __shared__ float wl[T_];
  __shared__ float red[16];
  __shared__ float pacc[4][64];
  const int tid = threadIdx.x;
  float mx = -1e30f;
  for (int t = tid; t < T_; t += 256) {
    float v = Srow[t] + (1.0f - mrow[t]) * -10000.0f;
    wl[t] = v;
    mx = fmaxf(mx, v);
  }
#pragma unroll
  for (int o = 32; o; o >>= 1) mx = fmaxf(mx, __shfl_xor(mx, o));
  if ((tid & 63) == 0) red[tid >> 6] = mx;
  __syncthreads();
  mx = fmaxf(fmaxf(red[0], red[1]), fmaxf(red[2], red[3]));
  float sum = 0.f;
  for (int t = tid; t < T_; t += 256) {
    float e = __expf(wl[t] - mx);
    wl[t] = e;
    sum += e;
  }
#pragma unroll
  for (int o = 32; o; o >>= 1) sum += __shfl_xor(sum, o);
  __syncthreads();   // wl writes done before pooling reads; red[0..3] reads done
  if ((tid & 63) == 0) red[8 + (tid >> 6)] = sum;
  __syncthreads();
  const float inv = 1.0f / (red[8] + red[9] + red[10] + red[11]);
  const int d = tid & 63, tp = tid >> 6;
  const short* Xb = X + (long)b * T_ * H_ + n * 64 + d;
  float a = 0.f;
  for (int t = tp; t < T_; t += 4)
    a += wl[t] * bf2f(Xb[(long)t * H_]);
  pacc[tp][d] = a;
  __syncthreads();
  if (tp == 0) {
    float r = (pacc[0][d] + pacc[1][d] + pacc[2][d] + pacc[3][d]) * inv;
    int h = n * 64 + d;
    if (pscale) r *= pscale[b * H_ + h];
    P[b * H_ + h] = r;
  }
}

// ---------------- Wkl'[b,n,h] = Wkl[n,h] * pq[b,h]  (f32 in, bf16 out) --------
__global__ __launch_bounds__(256) void scale_w2(
    const float* __restrict__ W, const float* __restrict__ pv, short* __restrict__ Wo) {
  int i = blockIdx.x * 256 + threadIdx.x;  // total B*NH*H = 131072
  int b = i >> 14;
  int j = i & 16383;
  int h = j & 1023;
  Wo[i] = f2bf(W[j] * pv[b * H_ + h]);
}

// ---------------- Wt'[b,j,h] = Wt[j,h] * pk[b,h]  (bf16 in, bf16 out) ---------
__global__ __launch_bounds__(256) void scale_wt(
    const short* __restrict__ Wt, const float* __restrict__ pk, short* __restrict__ Wo) {
  long i8 = (long)blockIdx.x * 256 + threadIdx.x;   // 1M threads
  long i = i8 * 8;                                   // total 8388608 elems
  int b = (int)(i >> 20);
  long j = i & 1048575;
  int h = (int)(j & 1023);
  short8 w = *((const short8*)Wt + (j >> 3));
  const float* pkb = pk + b * H_ + h;
  short8 o;
#pragma unroll
  for (int e = 0; e < 8; ++e) o[e] = f2bf(bf2f(w[e]) * pkb[e]);
  *((short8*)Wo + i8) = o;
}

extern "C" void kernel_launch(void* const* d_in, const int* in_sizes, int n_in,
                              void* d_out, int out_size, void* d_ws, size_t ws_size,
                              hipStream_t stream) {
  const float* hs   = (const float*)d_in[0];
  const float* mask = (const float*)d_in[1];
  const float* Wq   = (const float*)d_in[2];
  const float* bq   = (const float*)d_in[3];
  const float* Wk   = (const float*)d_in[4];
  const float* bk   = (const float*)d_in[5];
  const float* Wql  = (const float*)d_in[6];
  const float* bql  = (const float*)d_in[7];
  const float* Wkl  = (const float*)d_in[8];
  const float* bkl  = (const float*)d_in[9];
  const float* Wt   = (const float*)d_in[10];
  const float* bt   = (const float*)d_in[11];
  float* out = (float*)d_out;

  char* ws = (char*)d_ws;
  long off = 0;
  auto alloc = [&](long bytes) { char* p = ws + off; off += (bytes + 255) & ~255L; return p; };
  short* hs_bf  = (short*)alloc((long)M_ * H_ * 2);
  short* q_bf   = (short*)alloc((long)M_ * H_ * 2);
  short* k_bf   = (short*)alloc((long)M_ * H_ * 2);
  short* wq_bf  = (short*)alloc((long)H_ * H_ * 2);
  short* wk_bf  = (short*)alloc((long)H_ * H_ * 2);
  short* wt_bf  = (short*)alloc((long)H_ * H_ * 2);
  short* wql_bf = (short*)alloc((long)NH_ * H_ * 2);
  short* wkl_s  = (short*)alloc((long)B_ * NH_ * H_ * 2);
  short* wt_s   = (short*)alloc((long)B_ * H_ * H_ * 2);
  float* Sbuf   = (float*)alloc((long)B_ * NH_ * T_ * 4);
  float* pq     = (float*)alloc((long)B_ * H_ * 4);
  float* pk     = (float*)alloc((long)B_ * H_ * 4);

  // casts
  cast_f32_to_bf16<<<M_ * H_ / 8 / 256, 256, 0, stream>>>(hs, hs_bf, (long)M_ * H_ / 8);
  cast_f32_to_bf16<<<H_ * H_ / 8 / 256, 256, 0, stream>>>(Wq, wq_bf, (long)H_ * H_ / 8);
  cast_f32_to_bf16<<<H_ * H_ / 8 / 256, 256, 0, stream>>>(Wk, wk_bf, (long)H_ * H_ / 8);
  cast_f32_to_bf16<<<H_ * H_ / 8 / 256, 256, 0, stream>>>(Wt, wt_bf, (long)H_ * H_ / 8);
  cast_f32_to_bf16<<<NH_ * H_ / 8 / 256, 256, 0, stream>>>(Wql, wql_bf, (long)NH_ * H_ / 8);

  // q = hs @ Wq^T + bq ; k = hs @ Wk^T + bk   (bf16 out)
  dim3 g1(M_ / 128, H_ / 128, 1);
  gemm_bt<0><<<g1, 256, 0, stream>>>(hs_bf, wq_bf, bq, nullptr, q_bf, H_, H_, 0, 0, 0);
  gemm_bt<0><<<g1, 256, 0, stream>>>(hs_bf, wk_bf, bk, nullptr, k_bf, H_, H_, 0, 0, 0);

  // pooled q
  dim3 gs(T_ / 64, B_, 1);
  score_gemm<<<gs, 256, 0, stream>>>(q_bf, wql_bf, bql, Sbuf, 0);
  softmax_pool<<<B_ * NH_, 256, 0, stream>>>(Sbuf, mask, q_bf, nullptr, pq);

  // pooled k (pq folded into Wkl and into the pooling scale)
  scale_w2<<<B_ * NH_ * H_ / 256, 256, 0, stream>>>(Wkl, pq, wkl_s);
  score_gemm<<<gs, 256, 0, stream>>>(k_bf, wkl_s, bkl, Sbuf, (long)NH_ * H_);
  softmax_pool<<<B_ * NH_, 256, 0, stream>>>(Sbuf, mask, k_bf, pq, pk);

  // Wt'[b] = Wt * pk[b] ; out[b] = q[b] @ Wt'[b]^T + bt + q[b]
  scale_wt<<<B_ * H_ * H_ / 8 / 256, 256, 0, stream>>>(wt_bf, pk, wt_s);
  dim3 g2(T_ / 128, H_ / 128, B_);
  gemm_bt<1><<<g2, 256, 0, stream>>>(q_bf, wt_s, bt, q_bf, out, H_, H_,
                                     (long)T_ * H_, (long)H_ * H_, (long)T_ * H_);
}

// Round 4
// 607.845 us; speedup vs baseline: 1.7626x; 1.7626x over previous
//
#include <hip/hip_runtime.h>

#define B_ 8
#define T_ 4096
#define H_ 1024
#define NH_ 16
#define HD_ 64
#define M_ (B_*T_)   // 32768

typedef __attribute__((ext_vector_type(8))) short short8;
typedef __attribute__((ext_vector_type(4))) short short4v;
typedef __attribute__((ext_vector_type(4))) float floatx4;

__device__ __forceinline__ float bf2f(short s) {
  union { unsigned u; float f; } v; v.u = ((unsigned)(unsigned short)s) << 16; return v.f;
}
__device__ __forceinline__ short f2bf(float f) {
  union { float f; unsigned u; } v; v.f = f;
  unsigned r = (v.u + 0x7fffu + ((v.u >> 16) & 1u)) >> 16;
  return (short)r;
}

// ---------------- cast f32 -> bf16, 8 elems/thread ----------------
__global__ __launch_bounds__(256) void cast_f32_to_bf16(
    const float* __restrict__ src, short* __restrict__ dst, long n8) {
  long i = (long)blockIdx.x * 256 + threadIdx.x;
  if (i >= n8) return;
  const float4* s4 = (const float4*)src + i * 2;
  float4 a = s4[0], b = s4[1];
  short8 o;
  o[0] = f2bf(a.x); o[1] = f2bf(a.y); o[2] = f2bf(a.z); o[3] = f2bf(a.w);
  o[4] = f2bf(b.x); o[5] = f2bf(b.y); o[6] = f2bf(b.z); o[7] = f2bf(b.w);
  *((short8*)dst + i) = o;
}

// ---------------- 128x128 bf16 GEMM, C = A @ Bw^T (+bias, +resid) -------------
// A: [Mb, K] bf16 row-major, Bw: [N, K] bf16 row-major (B-transposed layout).
// EPI==0: out bf16 = acc + bias ; EPI==1: out f32 = acc + bias + resid(bf16)
template<int EPI>
__global__ __launch_bounds__(256, 2) void gemm_bt(
    const short* __restrict__ A, const short* __restrict__ Bw,
    const float* __restrict__ bias, const short* __restrict__ resid,
    void* __restrict__ out, int K, int N,
    long sA, long sB, long sO)
{
  __shared__ alignas(16) short As[128 * 64];
  __shared__ alignas(16) short Bs[128 * 64];
  const int tid = threadIdx.x;
  const int lane = tid & 63, wid = tid >> 6;
  const int bz = blockIdx.z;
  const short* Ab = A + (long)bz * sA;
  const short* Bb = Bw + (long)bz * sB;
  const int row0 = blockIdx.x * 128, col0 = blockIdx.y * 128;
  floatx4 acc[4][4] = {};
  const int wr = wid >> 1, wc = wid & 1;

  for (int k0 = 0; k0 < K; k0 += 64) {
#pragma unroll
    for (int it = 0; it < 4; ++it) {
      int c = it * 4 + wid;          // chunk 0..15, wave-uniform
      int e = c * 512 + lane * 8;    // element index within tile
      int r = e >> 6, cc = e & 63;
      __builtin_amdgcn_global_load_lds(
          (const __attribute__((address_space(1))) void*)(Ab + (long)(row0 + r) * K + k0 + cc),
          (__attribute__((address_space(3))) void*)(As + c * 512), 16, 0, 0);
      __builtin_amdgcn_global_load_lds(
          (const __attribute__((address_space(1))) void*)(Bb + (long)(col0 + r) * K + k0 + cc),
          (__attribute__((address_space(3))) void*)(Bs + c * 512), 16, 0, 0);
    }
    __syncthreads();
#pragma unroll
    for (int kk = 0; kk < 2; ++kk) {
      const int kof = kk * 32 + (lane >> 4) * 8;
      short8 af[4], bfv[4];
#pragma unroll
      for (int m = 0; m < 4; ++m)
        af[m] = *(const short8*)(As + (wr * 64 + m * 16 + (lane & 15)) * 64 + kof);
#pragma unroll
      for (int n = 0; n < 4; ++n)
        bfv[n] = *(const short8*)(Bs + (wc * 64 + n * 16 + (lane & 15)) * 64 + kof);
#pragma unroll
      for (int m = 0; m < 4; ++m)
#pragma unroll
        for (int n = 0; n < 4; ++n)
          acc[m][n] = __builtin_amdgcn_mfma_f32_16x16x32_bf16(af[m], bfv[n], acc[m][n], 0, 0, 0);
    }
    __syncthreads();
  }
#pragma unroll
  for (int n = 0; n < 4; ++n) {
    const int gc = col0 + wc * 64 + n * 16 + (lane & 15);
    const float bv = bias[gc];
#pragma unroll
    for (int m = 0; m < 4; ++m) {
      const int rbase = row0 + wr * 64 + m * 16 + ((lane >> 4) << 2);
#pragma unroll
      for (int i = 0; i < 4; ++i) {
        long idx = (long)bz * sO + (long)(rbase + i) * N + gc;
        float v = acc[m][n][i] + bv;
        if (EPI == 0) ((short*)out)[idx] = f2bf(v);
        else          ((float*)out)[idx] = v + bf2f(resid[idx]);
      }
    }
  }
}

// ---------------- score GEMM: S[b,n,t] = (X[b,t,:] . W2[(b),n,:] + bias[n])*0.125 ----
__global__ __launch_bounds__(256) void score_gemm(
    const short* __restrict__ X, const short* __restrict__ W2,
    const float* __restrict__ bias2, float* __restrict__ S, long sW)
{
  const int b = blockIdx.y;
  const int lane = threadIdx.x & 63, wid = threadIdx.x >> 6;
  const int t0 = blockIdx.x * 64 + wid * 16;
  const short* Xb = X + ((long)b * T_ + t0) * H_;
  const short* Wb = W2 + (long)b * sW;
  floatx4 acc = {};
  const int rr = lane & 15;
  const int kof = (lane >> 4) * 8;
#pragma unroll 8
  for (int k0 = 0; k0 < H_; k0 += 32) {
    short8 a = *(const short8*)(Xb + (long)rr * H_ + k0 + kof);
    short8 w = *(const short8*)(Wb + (long)rr * H_ + k0 + kof);
    acc = __builtin_amdgcn_mfma_f32_16x16x32_bf16(a, w, acc, 0, 0, 0);
  }
  const int n = lane & 15;
  const float bv = bias2[n];
#pragma unroll
  for (int i = 0; i < 4; ++i) {
    int t = t0 + (lane >> 4) * 4 + i;
    S[((long)b * NH_ + n) * T_ + t] = (acc[i] + bv) * 0.125f;
  }
}

// ---------------- softmax over T -> normalized weights; also zero P ----------
// grid = B*NH blocks of 256. w[bn,t] = softmax(S[bn,:] + maskadd)[t] ; P[bn*64+d]=0
__global__ __launch_bounds__(256) void softmax_w(
    const float* __restrict__ S, const float* __restrict__ mask,
    float* __restrict__ w, float* __restrict__ Pzero)
{
  const int bn = blockIdx.x, b = bn >> 4;
  const float* Srow = S + (long)bn * T_;
  const float* mrow = mask + (long)b * T_;
  __shared__ float buf[T_];
  __shared__ float red[8];
  const int tid = threadIdx.x;
  float mx = -1e30f;
  for (int t = tid; t < T_; t += 256) {
    float v = Srow[t] + (1.0f - mrow[t]) * -10000.0f;
    buf[t] = v;
    mx = fmaxf(mx, v);
  }
#pragma unroll
  for (int o = 32; o; o >>= 1) mx = fmaxf(mx, __shfl_xor(mx, o));
  if ((tid & 63) == 0) red[tid >> 6] = mx;
  __syncthreads();
  mx = fmaxf(fmaxf(red[0], red[1]), fmaxf(red[2], red[3]));
  float sum = 0.f;
  for (int t = tid; t < T_; t += 256) {
    float e = __expf(buf[t] - mx);
    buf[t] = e;
    sum += e;
  }
#pragma unroll
  for (int o = 32; o; o >>= 1) sum += __shfl_xor(sum, o);
  __syncthreads();
  if ((tid & 63) == 0) red[4 + (tid >> 6)] = sum;
  __syncthreads();
  const float inv = 1.0f / (red[4] + red[5] + red[6] + red[7]);
  float* wrow = w + (long)bn * T_;
  for (int t = tid; t < T_; t += 256) wrow[t] = buf[t] * inv;
  if (tid < 64) Pzero[bn * 64 + tid] = 0.f;
}

// ---------------- pooled vector: P[b, n*64+d] += sum_{t in chunk} w[t]*X[b,t,n*64+d]
// grid (B*NH, T/256), block 256. Vectorized short4 loads, atomic finalize.
__global__ __launch_bounds__(256) void pool_weighted(
    const float* __restrict__ w, const short* __restrict__ X,
    float* __restrict__ P)
{
  const int bn = blockIdx.x, b = bn >> 4, n = bn & 15;
  const int t0 = blockIdx.y * 256;
  const int tid = threadIdx.x;
  const int lane = tid & 63, wid = tid >> 6;
  const int c = lane & 15, r = lane >> 4;     // lane covers dims 4c..4c+3, row-slot r
  const float* wrow = w + (long)bn * T_ + t0;
  const short* Xb = X + ((long)b * T_ + t0) * H_ + n * 64 + c * 4;
  float a0 = 0.f, a1 = 0.f, a2 = 0.f, a3 = 0.f;
#pragma unroll 4
  for (int it = 0; it < 16; ++it) {
    const int t = it * 16 + wid * 4 + r;
    const float wt = wrow[t];
    short4v x = *(const short4v*)(Xb + (long)t * H_);
    a0 += wt * bf2f(x[0]);
    a1 += wt * bf2f(x[1]);
    a2 += wt * bf2f(x[2]);
    a3 += wt * bf2f(x[3]);
  }
  // reduce across the 4 row-slots (lanes c, c+16, c+32, c+48)
  a0 += __shfl_xor(a0, 16); a0 += __shfl_xor(a0, 32);
  a1 += __shfl_xor(a1, 16); a1 += __shfl_xor(a1, 32);
  a2 += __shfl_xor(a2, 16); a2 += __shfl_xor(a2, 32);
  a3 += __shfl_xor(a3, 16); a3 += __shfl_xor(a3, 32);
  __shared__ float pl[4][64];
  if (r == 0) {
    pl[wid][c * 4 + 0] = a0; pl[wid][c * 4 + 1] = a1;
    pl[wid][c * 4 + 2] = a2; pl[wid][c * 4 + 3] = a3;
  }
  __syncthreads();
  if (tid < 64) {
    float v = pl[0][tid] + pl[1][tid] + pl[2][tid] + pl[3][tid];
    atomicAdd(&P[bn * 64 + tid], v);
  }
}

// ---------------- Wkl'[b,n,h] = Wkl[n,h] * pq[b,h]  (f32 in, bf16 out) --------
__global__ __launch_bounds__(256) void scale_w2(
    const float* __restrict__ W, const float* __restrict__ pv, short* __restrict__ Wo) {
  int i = blockIdx.x * 256 + threadIdx.x;  // total B*NH*H = 131072
  int b = i >> 14;
  int j = i & 16383;
  int h = j & 1023;
  Wo[i] = f2bf(W[j] * pv[b * H_ + h]);
}

// -------- Wt'[b,j,h] = Wt[j,h] * pk_raw[b,h] * pq[b,h]  (bf16 in, bf16 out) ---
__global__ __launch_bounds__(256) void scale_wt(
    const short* __restrict__ Wt, const float* __restrict__ pkraw,
    const float* __restrict__ pq, short* __restrict__ Wo) {
  long i8 = (long)blockIdx.x * 256 + threadIdx.x;   // 1M threads
  long i = i8 * 8;
  int b = (int)(i >> 20);
  long j = i & 1048575;
  int h = (int)(j & 1023);
  short8 wv = *((const short8*)Wt + (j >> 3));
  const float* pa = pkraw + b * H_ + h;
  const float* pb = pq + b * H_ + h;
  short8 o;
#pragma unroll
  for (int e = 0; e < 8; ++e) o[e] = f2bf(bf2f(wv[e]) * pa[e] * pb[e]);
  *((short8*)Wo + i8) = o;
}

extern "C" void kernel_launch(void* const* d_in, const int* in_sizes, int n_in,
                              void* d_out, int out_size, void* d_ws, size_t ws_size,
                              hipStream_t stream) {
  const float* hs   = (const float*)d_in[0];
  const float* mask = (const float*)d_in[1];
  const float* Wq   = (const float*)d_in[2];
  const float* bq   = (const float*)d_in[3];
  const float* Wk   = (const float*)d_in[4];
  const float* bk   = (const float*)d_in[5];
  const float* Wql  = (const float*)d_in[6];
  const float* bql  = (const float*)d_in[7];
  const float* Wkl  = (const float*)d_in[8];
  const float* bkl  = (const float*)d_in[9];
  const float* Wt   = (const float*)d_in[10];
  const float* bt   = (const float*)d_in[11];
  float* out = (float*)d_out;

  char* ws = (char*)d_ws;
  long off = 0;
  auto alloc = [&](long bytes) { char* p = ws + off; off += (bytes + 255) & ~255L; return p; };
  short* hs_bf  = (short*)alloc((long)M_ * H_ * 2);
  short* q_bf   = (short*)alloc((long)M_ * H_ * 2);
  short* k_bf   = (short*)alloc((long)M_ * H_ * 2);
  short* wq_bf  = (short*)alloc((long)H_ * H_ * 2);
  short* wk_bf  = (short*)alloc((long)H_ * H_ * 2);
  short* wt_bf  = (short*)alloc((long)H_ * H_ * 2);
  short* wql_bf = (short*)alloc((long)NH_ * H_ * 2);
  short* wkl_s  = (short*)alloc((long)B_ * NH_ * H_ * 2);
  short* wt_s   = (short*)alloc((long)B_ * H_ * H_ * 2);
  float* Sbuf   = (float*)alloc((long)B_ * NH_ * T_ * 4);
  float* Wbuf   = (float*)alloc((long)B_ * NH_ * T_ * 4);
  float* pq     = (float*)alloc((long)B_ * H_ * 4);
  float* pk     = (float*)alloc((long)B_ * H_ * 4);

  // casts
  cast_f32_to_bf16<<<M_ * H_ / 8 / 256, 256, 0, stream>>>(hs, hs_bf, (long)M_ * H_ / 8);
  cast_f32_to_bf16<<<H_ * H_ / 8 / 256, 256, 0, stream>>>(Wq, wq_bf, (long)H_ * H_ / 8);
  cast_f32_to_bf16<<<H_ * H_ / 8 / 256, 256, 0, stream>>>(Wk, wk_bf, (long)H_ * H_ / 8);
  cast_f32_to_bf16<<<H_ * H_ / 8 / 256, 256, 0, stream>>>(Wt, wt_bf, (long)H_ * H_ / 8);
  cast_f32_to_bf16<<<NH_ * H_ / 8 / 256, 256, 0, stream>>>(Wql, wql_bf, (long)NH_ * H_ / 8);

  // q = hs @ Wq^T + bq ; k = hs @ Wk^T + bk   (bf16 out)
  dim3 g1(M_ / 128, H_ / 128, 1);
  gemm_bt<0><<<g1, 256, 0, stream>>>(hs_bf, wq_bf, bq, nullptr, q_bf, H_, H_, 0, 0, 0);
  gemm_bt<0><<<g1, 256, 0, stream>>>(hs_bf, wk_bf, bk, nullptr, k_bf, H_, H_, 0, 0, 0);

  // pooled q
  dim3 gs(T_ / 64, B_, 1);
  dim3 gp(B_ * NH_, T_ / 256, 1);
  score_gemm<<<gs, 256, 0, stream>>>(q_bf, wql_bf, bql, Sbuf, 0);
  softmax_w<<<B_ * NH_, 256, 0, stream>>>(Sbuf, mask, Wbuf, pq);
  pool_weighted<<<gp, 256, 0, stream>>>(Wbuf, q_bf, pq);

  // pooled k (pq folded into Wkl; pq modulation of pooled_k folded into scale_wt)
  scale_w2<<<B_ * NH_ * H_ / 256, 256, 0, stream>>>(Wkl, pq, wkl_s);
  score_gemm<<<gs, 256, 0, stream>>>(k_bf, wkl_s, bkl, Sbuf, (long)NH_ * H_);
  softmax_w<<<B_ * NH_, 256, 0, stream>>>(Sbuf, mask, Wbuf, pk);
  pool_weighted<<<gp, 256, 0, stream>>>(Wbuf, k_bf, pk);

  // Wt'[b] = Wt * pk_raw * pq ; out[b] = q[b] @ Wt'[b]^T + bt + q[b]
  scale_wt<<<B_ * H_ * H_ / 8 / 256, 256, 0, stream>>>(wt_bf, pk, pq, wt_s);
  dim3 g2(T_ / 128, H_ / 128, B_);
  gemm_bt<1><<<g2, 256, 0, stream>>>(q_bf, wt_s, bt, q_bf, out, H_, H_,
                                     (long)T_ * H_, (long)H_ * H_, (long)T_ * H_);
}